// Round 5
// baseline (578.728 us; speedup 1.0000x reference)
//
#include <hip/hip_runtime.h>
#include <math.h>

// Router: logits = x@Wg ; softmax ; top-2 ; renormalized combine.
// T=65536, D=1024, E=64. Out flat fp32: [combine 2T][idx-as-float 2T][probs 64T].
//
// R5: counter-separated operand feed. x: LDS double-buffer (lgkmcnt only).
// Weights: per-lane global vector loads (vmcnt only, L1/L2-served, lane-divergent
// expert-tile keeps them VMEM). Thread = 2 tokens x 8 experts = 16 acc.
// All-LDS feeding (R3/R4) was DS-pipe-bound (1.5 B/FMA vs 0.66 budget) and
// scratch-spilled; SMEM weights (R2) stalled on shared lgkmcnt. This does neither.

#define D_DIM 1024
#define E_DIM 64
#define TPB   256
#define TOK   64        // tokens per block
#define DC    32        // d-rows per chunk
#define NCH   (D_DIM / DC)
#define XS    36        // x tile stride: 144 B = 9*16, b128-aligned, measured ~0-conflict
#define LS    65        // logits tile stride

// 8 FMAs: one x scalar against 8 expert weights (two float4s), d fixed.
#define FMA8(A, xv, wA, wB)                                        \
    A[0] = fmaf(xv, wA.x, A[0]); A[1] = fmaf(xv, wA.y, A[1]);      \
    A[2] = fmaf(xv, wA.z, A[2]); A[3] = fmaf(xv, wA.w, A[3]);      \
    A[4] = fmaf(xv, wB.x, A[4]); A[5] = fmaf(xv, wB.y, A[5]);      \
    A[6] = fmaf(xv, wB.z, A[6]); A[7] = fmaf(xv, wB.w, A[7]);

__global__ __launch_bounds__(TPB, 4) void router_kernel(
    const float* __restrict__ x, const float* __restrict__ Wg,
    float* __restrict__ out, int T)
{
    __shared__ float sx[2][TOK * XS];   // 18432 B

    const int tid  = threadIdx.x;
    const int tt   = tid & 31;          // token pair: tt and tt+32
    const int e0   = (tid >> 5) << 3;   // experts e0..e0+7 (lane-divergent -> VMEM)
    const int base = blockIdx.x * TOK;

    float acc0[8], acc1[8];
#pragma unroll
    for (int j = 0; j < 8; ++j) { acc0[j] = 0.0f; acc1[j] = 0.0f; }

    // staging: x chunk = 64 tok x 32 d = 512 float4; 256 threads x 2 each
    const int xt0 = tid >> 3;           // 0..31 (and +32)
    const int xc0 = (tid & 7) << 2;     // 0..28
    const float* __restrict__ xr0 = x + (size_t)(base + xt0) * D_DIM + xc0;
    const float* __restrict__ xr1 = xr0 + (size_t)32 * D_DIM;

    float4 st0 = *(const float4*)xr0;
    float4 st1 = *(const float4*)xr1;
    *(float4*)&sx[0][xt0 * XS + xc0]        = st0;
    *(float4*)&sx[0][(xt0 + 32) * XS + xc0] = st1;
    st0 = *(const float4*)(xr0 + DC);
    st1 = *(const float4*)(xr1 + DC);
    __syncthreads();

    for (int ch = 0; ch < NCH; ++ch) {
        const int cur = ch & 1;
        if (ch + 1 < NCH) {             // regs hold chunk ch+1 -> other buffer
            *(float4*)&sx[cur ^ 1][xt0 * XS + xc0]        = st0;
            *(float4*)&sx[cur ^ 1][(xt0 + 32) * XS + xc0] = st1;
        }
        if (ch + 2 < NCH) {             // prefetch chunk ch+2 into regs
            st0 = *(const float4*)(xr0 + (ch + 2) * DC);
            st1 = *(const float4*)(xr1 + (ch + 2) * DC);
        }

        const float* __restrict__ bx = sx[cur];
        const float* __restrict__ wc = Wg + (size_t)ch * DC * E_DIM + e0;

#pragma unroll
        for (int g = 0; g < DC; g += 4) {
            const float4 xa = *(const float4*)&bx[tt * XS + g];          // token tt, d g..g+3
            const float4 xb = *(const float4*)&bx[(tt + 32) * XS + g];   // token tt+32
            const float4 w0a = *(const float4*)&wc[(size_t)(g + 0) * E_DIM];
            const float4 w0b = *(const float4*)&wc[(size_t)(g + 0) * E_DIM + 4];
            const float4 w1a = *(const float4*)&wc[(size_t)(g + 1) * E_DIM];
            const float4 w1b = *(const float4*)&wc[(size_t)(g + 1) * E_DIM + 4];
            const float4 w2a = *(const float4*)&wc[(size_t)(g + 2) * E_DIM];
            const float4 w2b = *(const float4*)&wc[(size_t)(g + 2) * E_DIM + 4];
            const float4 w3a = *(const float4*)&wc[(size_t)(g + 3) * E_DIM];
            const float4 w3b = *(const float4*)&wc[(size_t)(g + 3) * E_DIM + 4];
            // d ascending per accumulator: numerics identical to R2/R3/R4
            FMA8(acc0, xa.x, w0a, w0b)
            FMA8(acc0, xa.y, w1a, w1b)
            FMA8(acc0, xa.z, w2a, w2b)
            FMA8(acc0, xa.w, w3a, w3b)
            FMA8(acc1, xb.x, w0a, w0b)
            FMA8(acc1, xb.y, w1a, w1b)
            FMA8(acc1, xb.z, w2a, w2b)
            FMA8(acc1, xb.w, w3a, w3b)
        }
        __syncthreads();
    }

    // ---- logits -> LDS overlay on sx (4608 floats >= 64*65 = 4160) ----
    float* sl = &sx[0][0];
#pragma unroll
    for (int j = 0; j < 8; ++j) {
        sl[tt * LS + e0 + j]        = acc0[j];
        sl[(tt + 32) * LS + e0 + j] = acc1[j];
    }
    __syncthreads();

    // ---- epilogue: wave 0, one thread per token ----
    if (tid < TOK) {
        const int t = tid;
        float m = -INFINITY;
#pragma unroll
        for (int e = 0; e < E_DIM; ++e) m = fmaxf(m, sl[t * LS + e]);

        float s = 0.0f;
#pragma unroll
        for (int e = 0; e < E_DIM; ++e) {
            const float p = expf(sl[t * LS + e] - m);
            sl[t * LS + e] = p;
            s += p;
        }
        const float inv = 1.0f / s;

        float v1 = -1.0f, v2 = -1.0f;
        int   i1 = 0,     i2 = 0;
#pragma unroll
        for (int e = 0; e < E_DIM; ++e) {
            const float p = sl[t * LS + e] * inv;
            sl[t * LS + e] = p;
            if (p > v1)      { v2 = v1; i2 = i1; v1 = p; i1 = e; }
            else if (p > v2) { v2 = p;  i2 = e; }
        }

        const float denom = v1 + v2;
        const int token = base + t;
        *(float2*)&out[(size_t)2 * token]                 = make_float2(v1 / denom, v2 / denom);
        *(float2*)&out[(size_t)2 * T + (size_t)2 * token] = make_float2((float)i1, (float)i2);
    }
    __syncthreads();

    // ---- coalesced probs write: 16 KB block region, linear float4 ----
    float* __restrict__ po = out + (size_t)4 * T + (size_t)base * E_DIM;
#pragma unroll
    for (int k = 0; k < 4; ++k) {
        const int g = (tid + k * TPB) << 2;
        const int t = g >> 6;
        const int e = g & 63;
        *(float4*)&po[g] = make_float4(sl[t * LS + e],     sl[t * LS + e + 1],
                                       sl[t * LS + e + 2], sl[t * LS + e + 3]);
    }
}

extern "C" void kernel_launch(void* const* d_in, const int* in_sizes, int n_in,
                              void* d_out, int out_size, void* d_ws, size_t ws_size,
                              hipStream_t stream) {
    const float* x  = (const float*)d_in[0];
    const float* Wg = (const float*)d_in[1];
    float* out = (float*)d_out;
    const int T = in_sizes[0] / D_DIM;   // 65536

    router_kernel<<<dim3(T / TOK), dim3(TPB), 0, stream>>>(x, Wg, out, T);
}

// Round 6
// 404.255 us; speedup vs baseline: 1.4316x; 1.4316x over previous
//
#include <hip/hip_runtime.h>
#include <math.h>

// Router: logits = x@Wg ; softmax ; top-2 ; renormalized combine.
// T=65536, D=1024, E=64. Out flat fp32: [combine 2T][idx-as-float 2T][probs 64T].
//
// R6: both operands from LDS, tile sized so DS pipe < VALU pipe.
// Thread = 8 tokens x 4 experts (32 acc). Per 4-d group: 12 ds_read_b128
// (~144 cyc/wave) feeds 128 FMAs (256 cyc/wave) -> VALU-bound 0.56.
// w reads: 16 distinct addrs x 2-way broadcast = conflict-free (2-way is free).
// x reads: 4 distinct addrs (stride 20 -> distinct bank quads) x 16 broadcast.
// R5's per-lane global w loads were L1-return-BW-bound (1 KB/instr for 32 B
// useful -> ~218 us of L1 traffic); LDS broadcast eliminates the duplication.

#define D_DIM 1024
#define E_DIM 64
#define TPB   256
#define TOK   128       // tokens per block
#define DC    16        // d-rows per chunk
#define NCH   (D_DIM / DC)
#define XS    20        // x tile stride (floats): 16+4 pad; TG*20%32 hits 8 distinct quads
#define LS    65        // logits tile stride

__global__ __launch_bounds__(TPB, 2) void router_kernel(
    const float* __restrict__ x, const float* __restrict__ Wg,
    float* __restrict__ out, int T)
{
    // sx: 2 x 128 x 20 = 5120 floats | sw: 2 x 16 x 64 = 2048 floats
    // sl (post-GEMM overlay): 128 x 65 = 8320 floats
    __shared__ float smem[8448];
    float* const sx = smem;
    float* const sw = smem + 5120;

    const int tid  = threadIdx.x;
    const int eg   = tid & 15;         // expert group: experts eg*4 .. eg*4+3
    const int TG   = tid >> 4;         // token group: tokens TG + 16i, i=0..7
    const int e0   = eg << 2;
    const int base = blockIdx.x * TOK;

    float acc[8][4];
#pragma unroll
    for (int i = 0; i < 8; ++i)
#pragma unroll
        for (int j = 0; j < 4; ++j) acc[i][j] = 0.0f;

    // x staging: chunk = 128 tok x 16 d = 512 float4, 2 per thread
    const int xr0 = tid >> 2;               // 0..63   (and +64)
    const int xc0 = (tid & 3) << 2;         // 0,4,8,12
    const float* __restrict__ xg0 = x + (size_t)(base + xr0) * D_DIM + xc0;
    const float* __restrict__ xg1 = xg0 + (size_t)64 * D_DIM;
    // w staging: chunk = 16 d x 64 e = 256 float4, 1 per thread
    const int wd0 = tid >> 4;               // 0..15
    const int wc0 = (tid & 15) << 2;        // 0..60
    const float* __restrict__ wg0 = Wg + (size_t)wd0 * E_DIM + wc0;

    float4 xs0, xs1, wsr;

    // chunk 0 -> buf 0
    xs0 = *(const float4*)xg0;
    xs1 = *(const float4*)xg1;
    wsr = *(const float4*)wg0;
    *(float4*)&sx[xr0 * XS + xc0]        = xs0;
    *(float4*)&sx[(xr0 + 64) * XS + xc0] = xs1;
    *(float4*)&sw[wd0 * E_DIM + wc0]     = wsr;
    // prefetch chunk 1 into regs
    xs0 = *(const float4*)(xg0 + DC);
    xs1 = *(const float4*)(xg1 + DC);
    wsr = *(const float4*)(wg0 + (size_t)DC * E_DIM);
    __syncthreads();

    for (int ch = 0; ch < NCH; ++ch) {
        const int cur = ch & 1;
        if (ch + 1 < NCH) {   // regs hold chunk ch+1 -> other buffer
            float* const dx = sx + (cur ^ 1) * (TOK * XS);
            float* const dw = sw + (cur ^ 1) * (DC * E_DIM);
            *(float4*)&dx[xr0 * XS + xc0]        = xs0;
            *(float4*)&dx[(xr0 + 64) * XS + xc0] = xs1;
            *(float4*)&dw[wd0 * E_DIM + wc0]     = wsr;
        }
        if (ch + 2 < NCH) {   // prefetch chunk ch+2 (window = 1 full chunk)
            xs0 = *(const float4*)(xg0 + (ch + 2) * DC);
            xs1 = *(const float4*)(xg1 + (ch + 2) * DC);
            wsr = *(const float4*)(wg0 + (size_t)(ch + 2) * DC * E_DIM);
        }

        const float* __restrict__ bx = sx + cur * (TOK * XS);
        const float* __restrict__ bw = sw + cur * (DC * E_DIM);

#pragma unroll
        for (int g = 0; g < DC; g += 4) {
            const float4 w0 = *(const float4*)&bw[(g + 0) * E_DIM + e0];
            const float4 w1 = *(const float4*)&bw[(g + 1) * E_DIM + e0];
            const float4 w2 = *(const float4*)&bw[(g + 2) * E_DIM + e0];
            const float4 w3 = *(const float4*)&bw[(g + 3) * E_DIM + e0];
#pragma unroll
            for (int i = 0; i < 8; ++i) {
                const float4 xv = *(const float4*)&bx[(TG + 16 * i) * XS + g];
                // d ascending per accumulator: numerics identical to R2..R5
                acc[i][0] = fmaf(xv.x, w0.x, acc[i][0]);
                acc[i][0] = fmaf(xv.y, w1.x, acc[i][0]);
                acc[i][0] = fmaf(xv.z, w2.x, acc[i][0]);
                acc[i][0] = fmaf(xv.w, w3.x, acc[i][0]);
                acc[i][1] = fmaf(xv.x, w0.y, acc[i][1]);
                acc[i][1] = fmaf(xv.y, w1.y, acc[i][1]);
                acc[i][1] = fmaf(xv.z, w2.y, acc[i][1]);
                acc[i][1] = fmaf(xv.w, w3.y, acc[i][1]);
                acc[i][2] = fmaf(xv.x, w0.z, acc[i][2]);
                acc[i][2] = fmaf(xv.y, w1.z, acc[i][2]);
                acc[i][2] = fmaf(xv.z, w2.z, acc[i][2]);
                acc[i][2] = fmaf(xv.w, w3.z, acc[i][2]);
                acc[i][3] = fmaf(xv.x, w0.w, acc[i][3]);
                acc[i][3] = fmaf(xv.y, w1.w, acc[i][3]);
                acc[i][3] = fmaf(xv.z, w2.w, acc[i][3]);
                acc[i][3] = fmaf(xv.w, w3.w, acc[i][3]);
            }
        }
        __syncthreads();
    }

    // ---- logits -> LDS overlay (all waves past final barrier; sx/sw dead) ----
    float* const sl = smem;
#pragma unroll
    for (int i = 0; i < 8; ++i) {
        const int row = (TG + 16 * i) * LS + e0;
        sl[row + 0] = acc[i][0];
        sl[row + 1] = acc[i][1];
        sl[row + 2] = acc[i][2];
        sl[row + 3] = acc[i][3];
    }
    __syncthreads();

    // ---- epilogue: thread-per-token (tid < 128); bank (t+e)%32 distinct/lane ----
    if (tid < TOK) {
        const int t = tid;
        float m = -INFINITY;
#pragma unroll
        for (int e = 0; e < E_DIM; ++e) m = fmaxf(m, sl[t * LS + e]);

        float s = 0.0f;
#pragma unroll
        for (int e = 0; e < E_DIM; ++e) {
            const float p = expf(sl[t * LS + e] - m);
            sl[t * LS + e] = p;
            s += p;
        }
        const float inv = 1.0f / s;

        float v1 = -1.0f, v2 = -1.0f;
        int   i1 = 0,     i2 = 0;
#pragma unroll
        for (int e = 0; e < E_DIM; ++e) {
            const float p = sl[t * LS + e] * inv;
            sl[t * LS + e] = p;
            if (p > v1)      { v2 = v1; i2 = i1; v1 = p; i1 = e; }
            else if (p > v2) { v2 = p;  i2 = e; }
        }

        const float denom = v1 + v2;
        const int token = base + t;
        *(float2*)&out[(size_t)2 * token]                 = make_float2(v1 / denom, v2 / denom);
        *(float2*)&out[(size_t)2 * T + (size_t)2 * token] = make_float2((float)i1, (float)i2);
    }
    __syncthreads();

    // ---- coalesced probs write: 32 KB block region, linear float4 ----
    float* __restrict__ po = out + (size_t)4 * T + (size_t)base * E_DIM;
#pragma unroll
    for (int k = 0; k < 8; ++k) {
        const int g = (tid + k * TPB) << 2;
        const int t = g >> 6;
        const int e = g & 63;
        *(float4*)&po[g] = make_float4(sl[t * LS + e],     sl[t * LS + e + 1],
                                       sl[t * LS + e + 2], sl[t * LS + e + 3]);
    }
}

extern "C" void kernel_launch(void* const* d_in, const int* in_sizes, int n_in,
                              void* d_out, int out_size, void* d_ws, size_t ws_size,
                              hipStream_t stream) {
    const float* x  = (const float*)d_in[0];
    const float* Wg = (const float*)d_in[1];
    float* out = (float*)d_out;
    const int T = in_sizes[0] / D_DIM;   // 65536

    router_kernel<<<dim3(T / TOK), dim3(TPB), 0, stream>>>(x, Wg, out, T);
}